// Round 1
// baseline (1239.344 us; speedup 1.0000x reference)
//
#include <hip/hip_runtime.h>
#include <math.h>

#define B_ 8
#define N_ 4096
#define D_ 768
#define H_ 8
#define HD_ 96
#define FG_ 2049
#define TWO_PI 6.283185307179586476925f

__device__ __forceinline__ float gelu_f(float x) {
    return 0.5f * x * (1.0f + erff(x * 0.7071067811865475f));
}

__global__ void k_zero(float* p, int n) {
    int i = blockIdx.x * 256 + threadIdx.x;
    if (i < n) p[i] = 0.f;
}

// One block per (b,n) row: LayerNorm over D=768.
__global__ void k_layernorm(const float* __restrict__ x, const float* __restrict__ lw,
                            const float* __restrict__ lb, float* __restrict__ xn) {
    int row = blockIdx.x;  // b*N + n
    const float* xr = x + (size_t)row * D_;
    float* xo = xn + (size_t)row * D_;
    int t = threadIdx.x;
    float v0 = xr[t], v1 = xr[t + 256], v2 = xr[t + 512];
    __shared__ float red[256];
    red[t] = v0 + v1 + v2;
    __syncthreads();
    for (int o = 128; o > 0; o >>= 1) { if (t < o) red[t] += red[t + o]; __syncthreads(); }
    float mu = red[0] * (1.0f / 768.0f);
    __syncthreads();
    float d0 = v0 - mu, d1 = v1 - mu, d2 = v2 - mu;
    red[t] = d0 * d0 + d1 * d1 + d2 * d2;
    __syncthreads();
    for (int o = 128; o > 0; o >>= 1) { if (t < o) red[t] += red[t + o]; __syncthreads(); }
    float rstd = rsqrtf(red[0] * (1.0f / 768.0f) + 1e-5f);
    xo[t]       = d0 * rstd * lw[t]       + lb[t];
    xo[t + 256] = d1 * rstd * lw[t + 256] + lb[t + 256];
    xo[t + 512] = d2 * rstd * lw[t + 512] + lb[t + 512];
}

// ctx[b,d] = mean over n of xn[b,n,d]; hierarchical partial sums + atomicAdd.
__global__ void k_ctx(const float* __restrict__ xn, float* __restrict__ ctx) {
    int bx = blockIdx.x;                 // 0..383
    int dchunk = bx % 3, nchunk = (bx / 3) % 16, b = bx / 48;
    int d = dchunk * 256 + threadIdx.x;
    const float* base = xn + (size_t)b * N_ * D_ + d;
    int n0 = nchunk * 256;
    float s = 0.f;
    for (int i = 0; i < 256; ++i) s += base[(size_t)(n0 + i) * D_];
    atomicAdd(ctx + b * D_ + d, s * (1.0f / 4096.0f));
}

// [B][N][D] -> [B][D][N] tiled transpose
__global__ void k_transpose(const float* __restrict__ src, float* __restrict__ dst) {
    __shared__ float tile[64][65];
    int d0 = blockIdx.x * 64, n0 = blockIdx.y * 64, b = blockIdx.z;
    int c = threadIdx.x & 63, r4 = threadIdx.x >> 6;
    for (int q = 0; q < 16; ++q) {
        int r = r4 * 16 + q;
        tile[r][c] = src[((size_t)b * N_ + n0 + r) * D_ + d0 + c];
    }
    __syncthreads();
    for (int q = 0; q < 16; ++q) {
        int r = r4 * 16 + q;  // d-row
        dst[((size_t)b * D_ + d0 + r) * N_ + n0 + c] = tile[c][r];
    }
}

// h1g = gelu(ctx@w1g+b1g), h1l = gelu(ctx@w1l+b1l), hf = gelu(ctx@wf1+bf1)
__global__ void k_mlp1(const float* __restrict__ ctx,
                       const float* __restrict__ w1g, const float* __restrict__ b1g,
                       const float* __restrict__ w1l, const float* __restrict__ b1l,
                       const float* __restrict__ wf1, const float* __restrict__ bf1,
                       float* __restrict__ h1g, float* __restrict__ h1l, float* __restrict__ hf) {
    __shared__ float cl[B_ * D_];
    for (int i = threadIdx.x; i < B_ * D_; i += 256) cl[i] = ctx[i];
    __syncthreads();
    int c = blockIdx.x * 256 + threadIdx.x;
    if (c >= 1920) return;
    const float *w, *bias; float* out; int ncol, cc;
    if (c < 768)      { w = w1g; bias = b1g; out = h1g; ncol = 768; cc = c; }
    else if (c < 1536){ w = w1l; bias = b1l; out = h1l; ncol = 768; cc = c - 768; }
    else              { w = wf1; bias = bf1; out = hf;  ncol = 384; cc = c - 1536; }
    float acc[B_];
    #pragma unroll
    for (int b = 0; b < B_; ++b) acc[b] = 0.f;
    for (int d = 0; d < 768; ++d) {
        float wv = w[(size_t)d * ncol + cc];
        #pragma unroll
        for (int b = 0; b < B_; ++b) acc[b] += cl[b * 768 + d] * wv;
    }
    float bv = bias[cc];
    for (int b = 0; b < B_; ++b) out[b * ncol + cc] = gelu_f(acc[b] + bv);
}

// ag = h1g@w2g+b2g; al = h1l@w2l+b2l; gate = sigmoid(hf@wf2+bf2)
__global__ void k_mlp2(const float* __restrict__ h1g, const float* __restrict__ h1l,
                       const float* __restrict__ hf,
                       const float* __restrict__ w2g, const float* __restrict__ b2g,
                       const float* __restrict__ w2l, const float* __restrict__ b2l,
                       const float* __restrict__ wf2, const float* __restrict__ bf2,
                       float* __restrict__ ag, float* __restrict__ al, float* __restrict__ gate) {
    __shared__ float lg[B_ * 768];
    __shared__ float ll[B_ * 768];
    __shared__ float lf[B_ * 384];
    for (int i = threadIdx.x; i < B_ * 768; i += 256) { lg[i] = h1g[i]; ll[i] = h1l[i]; }
    for (int i = threadIdx.x; i < B_ * 384; i += 256) lf[i] = hf[i];
    __syncthreads();
    int c = blockIdx.x * 256 + threadIdx.x;
    const int CG = H_ * FG_ * 2;  // 32784
    float acc[B_];
    #pragma unroll
    for (int b = 0; b < B_; ++b) acc[b] = 0.f;
    if (c < CG) {
        for (int d = 0; d < 768; ++d) {
            float wv = w2g[(size_t)d * CG + c];
            #pragma unroll
            for (int b = 0; b < B_; ++b) acc[b] += lg[b * 768 + d] * wv;
        }
        float bv = b2g[c];
        for (int b = 0; b < B_; ++b) ag[(size_t)b * CG + c] = acc[b] + bv;
    } else if (c < CG + 80) {
        int cc = c - CG;
        for (int d = 0; d < 768; ++d) {
            float wv = w2l[d * 80 + cc];
            #pragma unroll
            for (int b = 0; b < B_; ++b) acc[b] += ll[b * 768 + d] * wv;
        }
        float bv = b2l[cc];
        for (int b = 0; b < B_; ++b) al[b * 80 + cc] = acc[b] + bv;
    } else if (c < CG + 80 + 8) {
        int cc = c - CG - 80;
        for (int d = 0; d < 384; ++d) {
            float wv = wf2[d * 8 + cc];
            #pragma unroll
            for (int b = 0; b < B_; ++b) acc[b] += lf[b * 384 + d] * wv;
        }
        float bv = bf2[cc];
        for (int b = 0; b < B_; ++b) gate[b * 8 + cc] = 1.0f / (1.0f + expf(-(acc[b] + bv)));
    }
}

__device__ __forceinline__ void fft_stages(float* re, float* im,
                                           const float* twr, const float* twi,
                                           int t, float sign) {
    for (int s = 1; s <= 12; ++s) {
        int half = 1 << (s - 1);
        int sh = 12 - s;
        for (int j = t; j < 2048; j += 256) {
            int grp = j >> (s - 1);
            int pos = j & (half - 1);
            int i1 = (grp << s) + pos;
            int i2 = i1 + half;
            int ti = pos << sh;
            float wr = twr[ti], wi = sign * twi[ti];
            float ar = re[i1], ai = im[i1];
            float br = re[i2], bi = im[i2];
            float tr = br * wr - bi * wi;
            float tii = br * wi + bi * wr;
            re[i1] = ar + tr;  im[i1] = ai + tii;
            re[i2] = ar - tr;  im[i2] = ai - tii;
        }
        __syncthreads();
    }
}

// One block per (b, d=h*96+hd) line: global FFT branch + local STFT branch + gate fusion.
__global__ __launch_bounds__(256) void k_spectral(
        const float* __restrict__ xt,    // [B][D][N]
        const float* __restrict__ ag,    // [B][32784]
        const float* __restrict__ al,    // [B][80]
        const float* __restrict__ gate,  // [B][8]
        const float* __restrict__ bf_g, const float* __restrict__ bb_g,
        const float* __restrict__ bf_l, const float* __restrict__ bb_l,
        float* __restrict__ fused)       // [B][D][N]
{
    __shared__ float re[4096];
    __shared__ float im[4096];
    __shared__ float twr[2048];
    __shared__ float twi[2048];
    int line = blockIdx.x;        // b*768 + d
    int d = line % 768, b = line / 768;
    int h = d / HD_;
    int t = threadIdx.x;

    // twiddle table W[k] = exp(-2*pi*i*k/4096)
    for (int k = t; k < 2048; k += 256) {
        float s, c;
        sincosf(-TWO_PI * (float)k / 4096.0f, &s, &c);
        twr[k] = c; twi[k] = s;
    }

    // load raw line (16 contiguous n per thread)
    const float* src = xt + (size_t)line * N_;
    float raw[16];
    #pragma unroll
    for (int q = 0; q < 4; ++q) {
        float4 v = ((const float4*)src)[t * 4 + q];
        raw[q * 4 + 0] = v.x; raw[q * 4 + 1] = v.y;
        raw[q * 4 + 2] = v.z; raw[q * 4 + 3] = v.w;
    }
    // deposit Hann-windowed, bit-reversed
    #pragma unroll
    for (int i = 0; i < 16; ++i) {
        int n = t * 16 + i;
        float wn = 0.5f - 0.5f * cosf(TWO_PI * (float)n / 4095.0f);
        int r = __brev((unsigned)n) >> 20;
        re[r] = raw[i] * wn;
        im[r] = 0.f;
    }

    // ---- local branch in registers (2 windows of 8 per thread) ----
    float alc = gate[b * 8 + h];
    const float* alb = al + b * 80;
    float effl_f[5], effl_b[5];
    #pragma unroll
    for (int f = 0; f < 5; ++f) {
        int idx = h * 5 + f;
        effl_f[f] = bf_l[idx] * (1.0f + alb[idx * 2]);
        effl_b[f] = bb_l[idx] + alb[idx * 2 + 1];
    }
    const float s8 = 0.3535533905932738f;  // 1/sqrt(8)
    const float c7 = 0.7071067811865476f;
    const float cosT[8] = {1.f, c7, 0.f, -c7, -1.f, -c7, 0.f, c7};
    const float sinT[8] = {0.f, c7, 1.f, c7, 0.f, -c7, -1.f, -c7};
    float hl[8];
    #pragma unroll
    for (int j = 0; j < 8; ++j) hl[j] = 0.5f - 0.5f * cosf(TWO_PI * (float)j / 7.0f);
    float xl[16];
    #pragma unroll
    for (int w2 = 0; w2 < 2; ++w2) {
        float xw[8];
        #pragma unroll
        for (int j = 0; j < 8; ++j) xw[j] = raw[w2 * 8 + j] * hl[j];
        float Yr[5], Yi[5];
        #pragma unroll
        for (int f = 0; f < 5; ++f) {
            float fr = 0.f, fi = 0.f;
            #pragma unroll
            for (int j = 0; j < 8; ++j) {
                int k8 = (f * j) & 7;
                fr += xw[j] * cosT[k8];
                fi -= xw[j] * sinT[k8];
            }
            fr *= s8; fi *= s8;
            float zr = fr * effl_f[f] + effl_b[f];
            float zi = fi * effl_f[f];
            float mag = sqrtf(zr * zr + zi * zi);
            float g = gelu_f(mag) / (mag + 1e-6f);
            Yr[f] = zr * g; Yi[f] = zi * g;
        }
        #pragma unroll
        for (int j = 0; j < 8; ++j) {
            float acc = Yr[0] + Yr[4] * ((j & 1) ? -1.f : 1.f);
            #pragma unroll
            for (int f = 1; f < 4; ++f) {
                int k8 = (f * j) & 7;
                acc += 2.f * (Yr[f] * cosT[k8] - Yi[f] * sinT[k8]);
            }
            xl[w2 * 8 + j] = acc * s8;
        }
    }

    __syncthreads();
    // forward FFT (input bit-reversed -> natural order spectrum)
    fft_stages(re, im, twr, twi, t, 1.0f);

    // modulate + complex GELU on k=0..2048 (ortho scale 1/64 folded in)
    const float inv64 = 1.0f / 64.0f;
    const float* agb = ag + (size_t)b * 32784;
    for (int k = t; k <= 2048; k += 256) {
        int idx = h * FG_ + k;
        float efff = bf_g[idx] * (1.0f + agb[idx * 2]);
        float effb = bb_g[idx] + agb[idx * 2 + 1];
        float zr = re[k] * inv64 * efff + effb;
        float zi = im[k] * inv64 * efff;
        float mag = sqrtf(zr * zr + zi * zi);
        float g = gelu_f(mag) / (mag + 1e-6f);
        re[k] = zr * g; im[k] = zi * g;
    }
    __syncthreads();
    // Hermitian extension
    for (int k = 2049 + t; k < 4096; k += 256) {
        re[k] = re[4096 - k];
        im[k] = -im[4096 - k];
    }
    __syncthreads();
    // in-place bit-reverse permutation
    for (int n = t; n < 4096; n += 256) {
        int r = __brev((unsigned)n) >> 20;
        if (r > n) {
            float a = re[n]; re[n] = re[r]; re[r] = a;
            float bb2 = im[n]; im[n] = im[r]; im[r] = bb2;
        }
    }
    __syncthreads();
    // inverse FFT (conjugate twiddles); x_global[n] = re[n]/64
    fft_stages(re, im, twr, twi, t, -1.0f);

    // fuse and store
    float* dst = fused + (size_t)line * N_;
    float one_m = 1.0f - alc;
    #pragma unroll
    for (int q = 0; q < 4; ++q) {
        float4 v;
        int base = t * 16 + q * 4;
        v.x = alc * re[base + 0] * inv64 + one_m * xl[q * 4 + 0];
        v.y = alc * re[base + 1] * inv64 + one_m * xl[q * 4 + 1];
        v.z = alc * re[base + 2] * inv64 + one_m * xl[q * 4 + 2];
        v.w = alc * re[base + 3] * inv64 + one_m * xl[q * 4 + 3];
        ((float4*)dst)[t * 4 + q] = v;
    }
}

// out[b,n,d] = x[b,n,d] + fused[b,d,n]  (tiled transpose-add)
__global__ void k_addout(const float* __restrict__ fused, const float* __restrict__ x,
                         float* __restrict__ out) {
    __shared__ float tile[64][65];
    int d0 = blockIdx.x * 64, n0 = blockIdx.y * 64, b = blockIdx.z;
    int c = threadIdx.x & 63, r4 = threadIdx.x >> 6;
    for (int q = 0; q < 16; ++q) {
        int r = r4 * 16 + q;  // d-row
        tile[r][c] = fused[((size_t)b * D_ + d0 + r) * N_ + n0 + c];
    }
    __syncthreads();
    for (int q = 0; q < 16; ++q) {
        int r = r4 * 16 + q;  // n-row
        size_t o = ((size_t)b * N_ + n0 + r) * D_ + d0 + c;
        out[o] = x[o] + tile[c][r];
    }
}

extern "C" void kernel_launch(void* const* d_in, const int* in_sizes, int n_in,
                              void* d_out, int out_size, void* d_ws, size_t ws_size,
                              hipStream_t stream) {
    const float* x    = (const float*)d_in[0];
    const float* ln_w = (const float*)d_in[1];
    const float* ln_b = (const float*)d_in[2];
    const float* bf_g = (const float*)d_in[3];
    const float* bb_g = (const float*)d_in[4];
    const float* bf_l = (const float*)d_in[5];
    const float* bb_l = (const float*)d_in[6];
    const float* w1g  = (const float*)d_in[7];
    const float* b1g  = (const float*)d_in[8];
    const float* w2g  = (const float*)d_in[9];
    const float* b2g  = (const float*)d_in[10];
    const float* w1l  = (const float*)d_in[11];
    const float* b1l  = (const float*)d_in[12];
    const float* w2l  = (const float*)d_in[13];
    const float* b2l  = (const float*)d_in[14];
    const float* wf1  = (const float*)d_in[15];
    const float* bf1  = (const float*)d_in[16];
    const float* wf2  = (const float*)d_in[17];
    const float* bf2  = (const float*)d_in[18];
    float* out = (float*)d_out;

    char* ws = (char*)d_ws;
    const size_t big = (size_t)B_ * D_ * N_ * sizeof(float);  // ~100.7 MB
    float* XT  = (float*)ws; ws += big;
    float* XN  = (float*)ws; ws += big;   // later reused as FUSED
    float* ctx = (float*)ws; ws += (size_t)B_ * D_ * 4;
    float* h1g = (float*)ws; ws += (size_t)B_ * 768 * 4;
    float* h1l = (float*)ws; ws += (size_t)B_ * 768 * 4;
    float* hf  = (float*)ws; ws += (size_t)B_ * 384 * 4;
    float* ag  = (float*)ws; ws += (size_t)B_ * 32784 * 4;
    float* alb = (float*)ws; ws += (size_t)B_ * 80 * 4;
    float* gat = (float*)ws; ws += (size_t)B_ * 8 * 4;

    k_zero<<<24, 256, 0, stream>>>(ctx, B_ * D_);
    k_layernorm<<<B_ * N_, 256, 0, stream>>>(x, ln_w, ln_b, XN);
    k_ctx<<<384, 256, 0, stream>>>(XN, ctx);
    k_transpose<<<dim3(12, 64, 8), 256, 0, stream>>>(XN, XT);
    k_mlp1<<<8, 256, 0, stream>>>(ctx, w1g, b1g, w1l, b1l, wf1, bf1, h1g, h1l, hf);
    k_mlp2<<<129, 256, 0, stream>>>(h1g, h1l, hf, w2g, b2g, w2l, b2l, wf2, bf2, ag, alb, gat);
    k_spectral<<<B_ * D_, 256, 0, stream>>>(XT, ag, alb, gat, bf_g, bb_g, bf_l, bb_l, XN);
    k_addout<<<dim3(12, 64, 8), 256, 0, stream>>>(XN, x, out);
}

// Round 2
// 705.579 us; speedup vs baseline: 1.7565x; 1.7565x over previous
//
#include <hip/hip_runtime.h>
#include <math.h>

#define B_ 8
#define N_ 4096
#define D_ 768
#define H_ 8
#define HD_ 96
#define FG_ 2049
#define TWO_PI 6.283185307179586476925f
// LDS anti-bank-conflict padding: one extra slot per 32
#define PAD(i) ((i) + ((i) >> 5))

__device__ __forceinline__ float gelu_f(float x) {
    return 0.5f * x * (1.0f + erff(x * 0.7071067811865475f));
}

__global__ void k_zero(float* p, int n) {
    int i = blockIdx.x * 256 + threadIdx.x;
    if (i < n) p[i] = 0.f;
}

// One block per (b,n) row: LayerNorm over D=768.
__global__ void k_layernorm(const float* __restrict__ x, const float* __restrict__ lw,
                            const float* __restrict__ lb, float* __restrict__ xn) {
    int row = blockIdx.x;  // b*N + n
    const float* xr = x + (size_t)row * D_;
    float* xo = xn + (size_t)row * D_;
    int t = threadIdx.x;
    float v0 = xr[t], v1 = xr[t + 256], v2 = xr[t + 512];
    __shared__ float red[256];
    red[t] = v0 + v1 + v2;
    __syncthreads();
    for (int o = 128; o > 0; o >>= 1) { if (t < o) red[t] += red[t + o]; __syncthreads(); }
    float mu = red[0] * (1.0f / 768.0f);
    __syncthreads();
    float d0 = v0 - mu, d1 = v1 - mu, d2 = v2 - mu;
    red[t] = d0 * d0 + d1 * d1 + d2 * d2;
    __syncthreads();
    for (int o = 128; o > 0; o >>= 1) { if (t < o) red[t] += red[t + o]; __syncthreads(); }
    float rstd = rsqrtf(red[0] * (1.0f / 768.0f) + 1e-5f);
    xo[t]       = d0 * rstd * lw[t]       + lb[t];
    xo[t + 256] = d1 * rstd * lw[t + 256] + lb[t + 256];
    xo[t + 512] = d2 * rstd * lw[t + 512] + lb[t + 512];
}

// ctx[b,d] = mean over n of xn[b,n,d]
__global__ void k_ctx(const float* __restrict__ xn, float* __restrict__ ctx) {
    int bx = blockIdx.x;                 // 0..383
    int dchunk = bx % 3, nchunk = (bx / 3) % 16, b = bx / 48;
    int d = dchunk * 256 + threadIdx.x;
    const float* base = xn + (size_t)b * N_ * D_ + d;
    int n0 = nchunk * 256;
    float s = 0.f;
    for (int i = 0; i < 256; ++i) s += base[(size_t)(n0 + i) * D_];
    atomicAdd(ctx + b * D_ + d, s * (1.0f / 4096.0f));
}

// [B][N][D] -> [B][D][N] tiled transpose
__global__ void k_transpose(const float* __restrict__ src, float* __restrict__ dst) {
    __shared__ float tile[64][65];
    int d0 = blockIdx.x * 64, n0 = blockIdx.y * 64, b = blockIdx.z;
    int c = threadIdx.x & 63, r4 = threadIdx.x >> 6;
    for (int q = 0; q < 16; ++q) {
        int r = r4 * 16 + q;
        tile[r][c] = src[((size_t)b * N_ + n0 + r) * D_ + d0 + c];
    }
    __syncthreads();
    for (int q = 0; q < 16; ++q) {
        int r = r4 * 16 + q;  // d-row
        dst[((size_t)b * D_ + d0 + r) * N_ + n0 + c] = tile[c][r];
    }
}

// h1g = gelu(ctx@w1g+b1g), h1l = gelu(ctx@w1l+b1l), hf = gelu(ctx@wf1+bf1)
__global__ void k_mlp1(const float* __restrict__ ctx,
                       const float* __restrict__ w1g, const float* __restrict__ b1g,
                       const float* __restrict__ w1l, const float* __restrict__ b1l,
                       const float* __restrict__ wf1, const float* __restrict__ bf1,
                       float* __restrict__ h1g, float* __restrict__ h1l, float* __restrict__ hf) {
    __shared__ float cl[B_ * D_];
    for (int i = threadIdx.x; i < B_ * D_; i += 256) cl[i] = ctx[i];
    __syncthreads();
    int c = blockIdx.x * 256 + threadIdx.x;
    if (c >= 1920) return;
    const float *w, *bias; float* out; int ncol, cc;
    if (c < 768)      { w = w1g; bias = b1g; out = h1g; ncol = 768; cc = c; }
    else if (c < 1536){ w = w1l; bias = b1l; out = h1l; ncol = 768; cc = c - 768; }
    else              { w = wf1; bias = bf1; out = hf;  ncol = 384; cc = c - 1536; }
    float acc[B_];
    #pragma unroll
    for (int b = 0; b < B_; ++b) acc[b] = 0.f;
    for (int d = 0; d < 768; ++d) {
        float wv = w[(size_t)d * ncol + cc];
        #pragma unroll
        for (int b = 0; b < B_; ++b) acc[b] += cl[b * 768 + d] * wv;
    }
    float bv = bias[cc];
    for (int b = 0; b < B_; ++b) out[b * ncol + cc] = gelu_f(acc[b] + bv);
}

// ag[b,c] = b2g[c]; al[b,c] = b2l[c]  (bias init for split-K accumulation)
__global__ void k_biasinit(const float* __restrict__ b2g, const float* __restrict__ b2l,
                           float* __restrict__ ag, float* __restrict__ al) {
    int c = blockIdx.x * 256 + threadIdx.x;
    const int CG = H_ * FG_ * 2;  // 32784
    if (c < CG) {
        float v = b2g[c];
        for (int b = 0; b < B_; ++b) ag[(size_t)b * CG + c] = v;
    } else if (c < CG + 80) {
        int cc = c - CG;
        float v = b2l[cc];
        for (int b = 0; b < B_; ++b) al[b * 80 + cc] = v;
    }
}

// split-K (4 chunks of 192): ag += h1g@w2g chunk; al += h1l@w2l chunk; gate full.
__global__ void k_mlp2(const float* __restrict__ h1g, const float* __restrict__ h1l,
                       const float* __restrict__ hf,
                       const float* __restrict__ w2g, const float* __restrict__ w2l,
                       const float* __restrict__ wf2, const float* __restrict__ bf2,
                       float* __restrict__ ag, float* __restrict__ al, float* __restrict__ gate) {
    int kc = blockIdx.y;       // 0..3
    int d0 = kc * 192;
    __shared__ float lg[B_ * 192];
    __shared__ float ll[B_ * 192];
    for (int i = threadIdx.x; i < B_ * 192; i += 256) {
        int bb = i / 192, dd = i % 192;
        lg[i] = h1g[bb * 768 + d0 + dd];
        ll[i] = h1l[bb * 768 + d0 + dd];
    }
    __syncthreads();
    int c = blockIdx.x * 256 + threadIdx.x;
    const int CG = H_ * FG_ * 2;  // 32784
    float acc[B_];
    #pragma unroll
    for (int b = 0; b < B_; ++b) acc[b] = 0.f;
    if (c < CG) {
        for (int d = 0; d < 192; ++d) {
            float wv = w2g[(size_t)(d0 + d) * CG + c];
            #pragma unroll
            for (int b = 0; b < B_; ++b) acc[b] += lg[b * 192 + d] * wv;
        }
        for (int b = 0; b < B_; ++b) atomicAdd(ag + (size_t)b * CG + c, acc[b]);
    } else if (c < CG + 80) {
        int cc = c - CG;
        for (int d = 0; d < 192; ++d) {
            float wv = w2l[(d0 + d) * 80 + cc];
            #pragma unroll
            for (int b = 0; b < B_; ++b) acc[b] += ll[b * 192 + d] * wv;
        }
        for (int b = 0; b < B_; ++b) atomicAdd(al + b * 80 + cc, acc[b]);
    } else if (c < CG + 88 && kc == 0) {
        int cc = c - CG - 80;
        for (int d = 0; d < 384; ++d) {
            float wv = wf2[d * 8 + cc];
            #pragma unroll
            for (int b = 0; b < B_; ++b) acc[b] += hf[b * 384 + d] * wv;
        }
        for (int b = 0; b < B_; ++b)
            gate[b * 8 + cc] = 1.0f / (1.0f + expf(-(acc[b] + bf2[cc])));
    }
}

__device__ __forceinline__ void fft_stages(float* re, float* im,
                                           const float* twr, const float* twi,
                                           int t, float sign) {
    for (int s = 1; s <= 12; ++s) {
        int half = 1 << (s - 1);
        int sh = 12 - s;
        for (int j = t; j < 2048; j += 256) {
            int grp = j >> (s - 1);
            int pos = j & (half - 1);
            int i1 = (grp << s) + pos;
            int i2 = i1 + half;
            int pt = PAD(pos << sh);
            int p1 = PAD(i1), p2 = PAD(i2);
            float wr = twr[pt], wi = sign * twi[pt];
            float ar = re[p1], ai = im[p1];
            float br = re[p2], bi = im[p2];
            float tr = br * wr - bi * wi;
            float tii = br * wi + bi * wr;
            re[p1] = ar + tr;  im[p1] = ai + tii;
            re[p2] = ar - tr;  im[p2] = ai - tii;
        }
        __syncthreads();
    }
}

// One block per PAIR of lines (2m, 2m+1): packed complex FFT does both.
__global__ __launch_bounds__(256) void k_spectral(
        const float* __restrict__ xt,    // [B][D][N]
        const float* __restrict__ ag,    // [B][32784]
        const float* __restrict__ al,    // [B][80]
        const float* __restrict__ gate,  // [B][8]
        const float* __restrict__ bf_g, const float* __restrict__ bb_g,
        const float* __restrict__ bf_l, const float* __restrict__ bb_l,
        float* __restrict__ fused)       // [B][D][N]
{
    __shared__ float re[4224];
    __shared__ float im[4224];
    __shared__ float twr[2112];
    __shared__ float twi[2112];
    int line0 = blockIdx.x * 2;   // b*768 + d0, d0 even
    int d0 = line0 % 768, b = line0 / 768;
    int h = d0 / HD_;             // both lines share h (HD=96 even)
    int t = threadIdx.x;

    // twiddle table W[k] = exp(-2*pi*i*k/4096), padded
    for (int k = t; k < 2048; k += 256) {
        float s, c;
        sincosf(-TWO_PI * (float)k / 4096.0f, &s, &c);
        twr[PAD(k)] = c; twi[PAD(k)] = s;
    }

    // load both raw lines (16 contiguous n per thread each)
    const float* src0 = xt + (size_t)line0 * N_;
    const float* src1 = src0 + N_;
    float raw0[16], raw1[16];
    #pragma unroll
    for (int q = 0; q < 4; ++q) {
        float4 v0 = ((const float4*)src0)[t * 4 + q];
        float4 v1 = ((const float4*)src1)[t * 4 + q];
        raw0[q * 4 + 0] = v0.x; raw0[q * 4 + 1] = v0.y;
        raw0[q * 4 + 2] = v0.z; raw0[q * 4 + 3] = v0.w;
        raw1[q * 4 + 0] = v1.x; raw1[q * 4 + 1] = v1.y;
        raw1[q * 4 + 2] = v1.z; raw1[q * 4 + 3] = v1.w;
    }
    // deposit packed complex z = x0 + i*x1, Hann-windowed, bit-reversed
    #pragma unroll
    for (int i = 0; i < 16; ++i) {
        int n = t * 16 + i;
        float wn = 0.5f - 0.5f * cosf(TWO_PI * (float)n / 4095.0f);
        int r = PAD((int)(__brev((unsigned)n) >> 20));
        re[r] = raw0[i] * wn;
        im[r] = raw1[i] * wn;
    }

    // ---- local branch in registers (2 windows of 8 per thread, both lines) ----
    float alc = gate[b * 8 + h];
    const float* alb = al + b * 80;
    float effl_f[5], effl_b[5];
    #pragma unroll
    for (int f = 0; f < 5; ++f) {
        int idx = h * 5 + f;
        effl_f[f] = bf_l[idx] * (1.0f + alb[idx * 2]);
        effl_b[f] = bb_l[idx] + alb[idx * 2 + 1];
    }
    const float s8 = 0.3535533905932738f;  // 1/sqrt(8)
    const float c7 = 0.7071067811865476f;
    const float cosT[8] = {1.f, c7, 0.f, -c7, -1.f, -c7, 0.f, c7};
    const float sinT[8] = {0.f, c7, 1.f, c7, 0.f, -c7, -1.f, -c7};
    float hl[8];
    #pragma unroll
    for (int j = 0; j < 8; ++j) hl[j] = 0.5f - 0.5f * cosf(TWO_PI * (float)j / 7.0f);
    float xl0[16], xl1[16];
    #pragma unroll
    for (int ln = 0; ln < 2; ++ln) {
        float* rawp = ln ? raw1 : raw0;
        float* xlp  = ln ? xl1 : xl0;
        #pragma unroll
        for (int w2 = 0; w2 < 2; ++w2) {
            float xw[8];
            #pragma unroll
            for (int j = 0; j < 8; ++j) xw[j] = rawp[w2 * 8 + j] * hl[j];
            float Yr[5], Yi[5];
            #pragma unroll
            for (int f = 0; f < 5; ++f) {
                float fr = 0.f, fi = 0.f;
                #pragma unroll
                for (int j = 0; j < 8; ++j) {
                    int k8 = (f * j) & 7;
                    fr += xw[j] * cosT[k8];
                    fi -= xw[j] * sinT[k8];
                }
                fr *= s8; fi *= s8;
                float zr = fr * effl_f[f] + effl_b[f];
                float zi = fi * effl_f[f];
                float mag = sqrtf(zr * zr + zi * zi);
                float g = gelu_f(mag) / (mag + 1e-6f);
                Yr[f] = zr * g; Yi[f] = zi * g;
            }
            #pragma unroll
            for (int j = 0; j < 8; ++j) {
                float acc = Yr[0] + Yr[4] * ((j & 1) ? -1.f : 1.f);
                #pragma unroll
                for (int f = 1; f < 4; ++f) {
                    int k8 = (f * j) & 7;
                    acc += 2.f * (Yr[f] * cosT[k8] - Yi[f] * sinT[k8]);
                }
                xlp[w2 * 8 + j] = acc * s8;
            }
        }
    }

    __syncthreads();
    // forward FFT: Z = FFT(x0 + i*x1), natural order out
    fft_stages(re, im, twr, twi, t, 1.0f);

    // Hermitian split + modulate + cgelu + re-pack (in place; thread owns {k, 4096-k})
    const float inv64 = 1.0f / 64.0f;
    const float* agb = ag + (size_t)b * 32784;
    for (int k = t; k < 2048; k += 256) {
        int km = (4096 - k) & 4095;
        int pk = PAD(k), pm = PAD(km);
        float Zr = re[pk], Zi = im[pk];
        float Zr2 = re[pm], Zi2 = im[pm];
        float X0r = 0.5f * (Zr + Zr2), X0i = 0.5f * (Zi - Zi2);
        float X1r = 0.5f * (Zi + Zi2), X1i = -0.5f * (Zr - Zr2);
        int idx = h * FG_ + k;
        float efff = bf_g[idx] * (1.0f + agb[idx * 2]);
        float effb = bb_g[idx] + agb[idx * 2 + 1];
        float z0r = X0r * inv64 * efff + effb, z0i = X0i * inv64 * efff;
        float m0 = sqrtf(z0r * z0r + z0i * z0i);
        float g0 = gelu_f(m0) / (m0 + 1e-6f);
        float Y0r = z0r * g0, Y0i = z0i * g0;
        float z1r = X1r * inv64 * efff + effb, z1i = X1i * inv64 * efff;
        float m1 = sqrtf(z1r * z1r + z1i * z1i);
        float g1 = gelu_f(m1) / (m1 + 1e-6f);
        float Y1r = z1r * g1, Y1i = z1i * g1;
        re[pk] = Y0r - Y1i;  im[pk] = Y0i + Y1r;
        if (k) { re[pm] = Y0r + Y1i; im[pm] = Y1r - Y0i; }
    }
    if (t == 0) {  // Nyquist bin k=2048 (self-mirror; X0,X1 real)
        int pk = PAD(2048);
        float Zr = re[pk], Zi = im[pk];
        int idx = h * FG_ + 2048;
        float efff = bf_g[idx] * (1.0f + agb[idx * 2]);
        float effb = bb_g[idx] + agb[idx * 2 + 1];
        float z0r = Zr * inv64 * efff + effb;
        float m0 = fabsf(z0r);
        float Y0r = z0r * (gelu_f(m0) / (m0 + 1e-6f));
        float z1r = Zi * inv64 * efff + effb;
        float m1 = fabsf(z1r);
        float Y1r = z1r * (gelu_f(m1) / (m1 + 1e-6f));
        re[pk] = Y0r;  im[pk] = Y1r;
    }
    __syncthreads();
    // bit-reverse permutation (padded)
    for (int n = t; n < 4096; n += 256) {
        int r = (int)(__brev((unsigned)n) >> 20);
        if (r > n) {
            int pn = PAD(n), pr = PAD(r);
            float a = re[pn]; re[pn] = re[pr]; re[pr] = a;
            float bb2 = im[pn]; im[pn] = im[pr]; im[pr] = bb2;
        }
    }
    __syncthreads();
    // inverse FFT: w = N*IDFT(P); y0 = Re(w)/64, y1 = Im(w)/64
    fft_stages(re, im, twr, twi, t, -1.0f);

    // fuse and store both lines
    float* dst0 = fused + (size_t)line0 * N_;
    float* dst1 = dst0 + N_;
    float one_m = 1.0f - alc;
    #pragma unroll
    for (int q = 0; q < 4; ++q) {
        float4 v0, v1;
        int base = t * 16 + q * 4;
        v0.x = alc * re[PAD(base + 0)] * inv64 + one_m * xl0[q * 4 + 0];
        v0.y = alc * re[PAD(base + 1)] * inv64 + one_m * xl0[q * 4 + 1];
        v0.z = alc * re[PAD(base + 2)] * inv64 + one_m * xl0[q * 4 + 2];
        v0.w = alc * re[PAD(base + 3)] * inv64 + one_m * xl0[q * 4 + 3];
        v1.x = alc * im[PAD(base + 0)] * inv64 + one_m * xl1[q * 4 + 0];
        v1.y = alc * im[PAD(base + 1)] * inv64 + one_m * xl1[q * 4 + 1];
        v1.z = alc * im[PAD(base + 2)] * inv64 + one_m * xl1[q * 4 + 2];
        v1.w = alc * im[PAD(base + 3)] * inv64 + one_m * xl1[q * 4 + 3];
        ((float4*)dst0)[t * 4 + q] = v0;
        ((float4*)dst1)[t * 4 + q] = v1;
    }
}

// out[b,n,d] = x[b,n,d] + fused[b,d,n]  (tiled transpose-add)
__global__ void k_addout(const float* __restrict__ fused, const float* __restrict__ x,
                         float* __restrict__ out) {
    __shared__ float tile[64][65];
    int d0 = blockIdx.x * 64, n0 = blockIdx.y * 64, b = blockIdx.z;
    int c = threadIdx.x & 63, r4 = threadIdx.x >> 6;
    for (int q = 0; q < 16; ++q) {
        int r = r4 * 16 + q;  // d-row
        tile[r][c] = fused[((size_t)b * D_ + d0 + r) * N_ + n0 + c];
    }
    __syncthreads();
    for (int q = 0; q < 16; ++q) {
        int r = r4 * 16 + q;  // n-row
        size_t o = ((size_t)b * N_ + n0 + r) * D_ + d0 + c;
        out[o] = x[o] + tile[c][r];
    }
}

extern "C" void kernel_launch(void* const* d_in, const int* in_sizes, int n_in,
                              void* d_out, int out_size, void* d_ws, size_t ws_size,
                              hipStream_t stream) {
    const float* x    = (const float*)d_in[0];
    const float* ln_w = (const float*)d_in[1];
    const float* ln_b = (const float*)d_in[2];
    const float* bf_g = (const float*)d_in[3];
    const float* bb_g = (const float*)d_in[4];
    const float* bf_l = (const float*)d_in[5];
    const float* bb_l = (const float*)d_in[6];
    const float* w1g  = (const float*)d_in[7];
    const float* b1g  = (const float*)d_in[8];
    const float* w2g  = (const float*)d_in[9];
    const float* b2g  = (const float*)d_in[10];
    const float* w1l  = (const float*)d_in[11];
    const float* b1l  = (const float*)d_in[12];
    const float* w2l  = (const float*)d_in[13];
    const float* b2l  = (const float*)d_in[14];
    const float* wf1  = (const float*)d_in[15];
    const float* bf1  = (const float*)d_in[16];
    const float* wf2  = (const float*)d_in[17];
    const float* bf2  = (const float*)d_in[18];
    float* out = (float*)d_out;

    char* ws = (char*)d_ws;
    const size_t big = (size_t)B_ * D_ * N_ * sizeof(float);  // ~100.7 MB
    float* XT  = (float*)ws; ws += big;
    float* XN  = (float*)ws; ws += big;   // later reused as FUSED
    float* ctx = (float*)ws; ws += (size_t)B_ * D_ * 4;
    float* h1g = (float*)ws; ws += (size_t)B_ * 768 * 4;
    float* h1l = (float*)ws; ws += (size_t)B_ * 768 * 4;
    float* hf  = (float*)ws; ws += (size_t)B_ * 384 * 4;
    float* ag  = (float*)ws; ws += (size_t)B_ * 32784 * 4;
    float* alb = (float*)ws; ws += (size_t)B_ * 80 * 4;
    float* gat = (float*)ws; ws += (size_t)B_ * 8 * 4;

    k_zero<<<24, 256, 0, stream>>>(ctx, B_ * D_);
    k_layernorm<<<B_ * N_, 256, 0, stream>>>(x, ln_w, ln_b, XN);
    k_ctx<<<384, 256, 0, stream>>>(XN, ctx);
    k_transpose<<<dim3(12, 64, 8), 256, 0, stream>>>(XN, XT);
    k_mlp1<<<8, 256, 0, stream>>>(ctx, w1g, b1g, w1l, b1l, wf1, bf1, h1g, h1l, hf);
    k_biasinit<<<129, 256, 0, stream>>>(b2g, b2l, ag, alb);
    k_mlp2<<<dim3(129, 4), 256, 0, stream>>>(h1g, h1l, hf, w2g, w2l, wf2, bf2, ag, alb, gat);
    k_spectral<<<B_ * D_ / 2, 256, 0, stream>>>(XT, ag, alb, gat, bf_g, bb_g, bf_l, bb_l, XN);
    k_addout<<<dim3(12, 64, 8), 256, 0, stream>>>(XN, x, out);
}